// Round 4
// baseline (172.381 us; speedup 1.0000x reference)
//
#include <hip/hip_runtime.h>

#define NT 16
#define NTILES 256
#define INV_TILE (1.0f/64.0f)
#define CHUNK 2048          // points per block
#define WPT (CHUNK/4)       // 512 points per wave
#define ROUNDS (WPT/64)     // 8

__device__ __forceinline__ int tile_of(float x, float y) {
    int tx = (int)floorf(x * INV_TILE);
    tx = tx < 0 ? 0 : (tx > NT - 1 ? NT - 1 : tx);
    int ty = (int)floorf(y * INV_TILE);
    ty = ty < 0 ? 0 : (ty > NT - 1 ? NT - 1 : ty);
    return ty * NT + tx;
}

// 64-lane same-tile group mask via 8 ballots (tile id is 8 bits).
__device__ __forceinline__ unsigned long long match_mask(int t, bool valid) {
    unsigned long long m = ~0ull;
#pragma unroll
    for (int b = 0; b < 8; ++b) {
        unsigned long long bal = __ballot((t >> b) & 1);
        m &= ((t >> b) & 1) ? bal : ~bal;
    }
    m &= __ballot(valid);
    return m;
}

// K1: per-chunk (per-block) 256-bin histogram + global tile totals.
__global__ __launch_bounds__(256) void k_hist(const float2* __restrict__ pos2d,
                                              int* __restrict__ gHist,
                                              int* __restrict__ gcounts,
                                              int N) {
    __shared__ int counters[4][NTILES];
    const int tid = threadIdx.x;
    const int wl = tid >> 6, lane = tid & 63;
#pragma unroll
    for (int k = 0; k < 4; ++k) counters[wl][lane + 64 * k] = 0;  // wave-private
    const int wstart = blockIdx.x * CHUNK + wl * WPT;
    for (int r = 0; r < ROUNDS; ++r) {
        int i = wstart + r * 64 + lane;
        bool valid = i < N;
        int t = 0;
        if (valid) { float2 p = pos2d[i]; t = tile_of(p.x, p.y); }
        unsigned long long m = match_mask(t, valid);
        if (valid) {
            unsigned long long below = m & ((1ull << lane) - 1ull);
            if (below == 0ull) counters[wl][t] += __popcll(m);
        }
    }
    __syncthreads();
    int s = counters[0][tid] + counters[1][tid] + counters[2][tid] + counters[3][tid];
    gHist[(size_t)blockIdx.x * NTILES + tid] = s;
    if (s) atomicAdd(&gcounts[tid], s);
}

// K2: one block per tile. Cross-tile exclusive offset + column scan of the
// per-chunk hist rows (converted in place into per-chunk output bases).
// Supports up to 1024 chunk rows (N <= 2.097M at CHUNK=2048).
__global__ __launch_bounds__(256) void k_scan(const int* __restrict__ gcounts,
                                              int* __restrict__ gHist,
                                              float* __restrict__ out_counts,
                                              float* __restrict__ out_offsets,
                                              int NWA) {
    const int t = blockIdx.x;
    const int tid = threadIdx.x;
    const int wl = tid >> 6, lane = tid & 63;
    __shared__ int sdata[NTILES];
    __shared__ int wsum[4];

    int v = (tid < t) ? gcounts[tid] : 0;            // offset_t = sum_{u<t}
    sdata[tid] = v;
    __syncthreads();
#pragma unroll
    for (int s = 128; s > 0; s >>= 1) {
        if (tid < s) sdata[tid] += sdata[tid + s];
        __syncthreads();
    }
    int offset_t = sdata[0];
    if (tid == 0) {
        out_counts[t]  = (float)gcounts[t];
        out_offsets[t] = (float)offset_t;
    }

    int vals[4];
    const int base_row = tid * 4;
#pragma unroll
    for (int k = 0; k < 4; ++k) {
        int row = base_row + k;
        vals[k] = (row < NWA) ? gHist[(size_t)row * NTILES + t] : 0;
    }
    int tv = vals[0] + vals[1] + vals[2] + vals[3];
    int x = tv;
#pragma unroll
    for (int s = 1; s < 64; s <<= 1) {
        int y = __shfl_up(x, s);
        if (lane >= s) x += y;
    }
    if (lane == 63) wsum[wl] = x;
    __syncthreads();
    int wprefix = 0;
    for (int u = 0; u < wl; ++u) wprefix += wsum[u];
    int running = offset_t + wprefix + (x - tv);
#pragma unroll
    for (int k = 0; k < 4; ++k) {
        int row = base_row + k;
        if (row < NWA) gHist[(size_t)row * NTILES + t] = running;
        running += vals[k];
    }
}

// K3: block-staged stable scatter, all-coalesced global traffic.
// pass1: coalesced pos2d -> tileid[] in LDS + per-wave hist.
// scan:  per-tile block-local starts + per-wave bases.
// pass2: coalesced cov2d + opacity; t from LDS; ballot rank -> stash raw
//        (a,b,d,op) float4 + packed (t,o) at block-local sorted position.
//        (cov2d is symmetric: b==c bitwise, so det = a*d - b*b is exact.)
// write: conic/radius math here (VALU idle); pos2d gather L1-resident
//        (16KB/block); global writes are coalesced per-tile runs.
// LDS ~49 KB -> 3 blocks/CU.
__global__ __launch_bounds__(256) void k_scatter(const float2* __restrict__ pos2d,
                                                 const float4* __restrict__ cov2d,
                                                 const float*  __restrict__ opacity,
                                                 const int*    __restrict__ gBase,
                                                 float* __restrict__ out_feat,
                                                 float* __restrict__ out_order,
                                                 int N) {
    __shared__ float4 featS[CHUNK];           // (a, b, d, op) at sorted pos
    __shared__ unsigned int slotPk[CHUNK];    // (t<<16) | o  at sorted pos
    __shared__ unsigned char tileid[CHUNK];   // tile id at input pos
    __shared__ int cnt[4][NTILES];
    __shared__ int tstart[NTILES];
    __shared__ int gbase[NTILES];
    __shared__ int wsum[4];

    const int tid = threadIdx.x;
    const int wl = tid >> 6, lane = tid & 63;
    const int base_i = blockIdx.x * CHUNK;

    gbase[tid] = gBase[(size_t)blockIdx.x * NTILES + tid];   // coalesced 1KB row
#pragma unroll
    for (int k = 0; k < 4; ++k) cnt[wl][lane + 64 * k] = 0;  // wave-private

    const int wstart = base_i + wl * WPT;
    // ---- pass 1: tile ids -> LDS + per-wave histogram ----
    for (int r = 0; r < ROUNDS; ++r) {
        int i = wstart + r * 64 + lane;
        bool valid = i < N;
        int t = 0;
        if (valid) { float2 p = pos2d[i]; t = tile_of(p.x, p.y); }
        tileid[wl * WPT + r * 64 + lane] = (unsigned char)t;
        unsigned long long m = match_mask(t, valid);
        if (valid) {
            unsigned long long below = m & ((1ull << lane) - 1ull);
            if (below == 0ull) cnt[wl][t] += __popcll(m);
        }
    }
    __syncthreads();

    // ---- block scan: per-tile start + per-wave bases (thread tid = tile) ----
    int c0_ = cnt[0][tid], c1_ = cnt[1][tid], c2_ = cnt[2][tid], c3_ = cnt[3][tid];
    int tot = c0_ + c1_ + c2_ + c3_;
    int x = tot;
#pragma unroll
    for (int s = 1; s < 64; s <<= 1) {
        int y = __shfl_up(x, s);
        if (lane >= s) x += y;
    }
    if (lane == 63) wsum[wl] = x;
    __syncthreads();
    int wpre = 0;
    for (int u = 0; u < wl; ++u) wpre += wsum[u];
    int excl = wpre + x - tot;                 // block-exclusive start of tile tid
    tstart[tid] = excl;
    cnt[0][tid] = excl;
    cnt[1][tid] = excl + c0_;
    cnt[2][tid] = excl + c0_ + c1_;
    cnt[3][tid] = excl + c0_ + c1_ + c2_;
    __syncthreads();

    // ---- pass 2: stable rank -> stash raw cov row at sorted position ----
    for (int r = 0; r < ROUNDS; ++r) {
        int o = wl * WPT + r * 64 + lane;
        int i = base_i + o;
        bool valid = i < N;
        int t = tileid[o];
        float4 st = make_float4(0.f, 0.f, 0.f, 0.f);
        if (valid) {
            float4 cv = cov2d[i];              // only read, coalesced
            st = make_float4(cv.x, cv.y, cv.w, opacity[i]);   // a, b, d, op
        }
        unsigned long long m = match_mask(t, valid);
        if (valid) {
            unsigned long long below = m & ((1ull << lane) - 1ull);
            int rank = __popcll(below);
            int b = cnt[wl][t];                          // lockstep read-before-write
            if (below == 0ull) cnt[wl][t] = b + __popcll(m);
            int ldest = b + rank;                        // block-local sorted pos
            featS[ldest] = st;
            slotPk[ldest] = ((unsigned int)t << 16) | (unsigned int)o;
        }
    }
    __syncthreads();

    // ---- write-out: conic/radius math + coalesced per-tile segments ----
    int nvalid = N - base_i;
    if (nvalid > CHUNK) nvalid = CHUNK;
    for (int j = tid; j < nvalid; j += 256) {
        unsigned int pk = slotPk[j];
        int t = pk >> 16;
        int o = pk & 0xFFFF;
        int gdest = gbase[t] + (j - tstart[t]);
        int i = base_i + o;
        float2 p = pos2d[i];                   // L1-resident gather (16KB/block)
        float4 st = featS[j];
        float a = st.x, b = st.y, d = st.z, op = st.w;
        float trace = a + d;
        float det = a * d - b * b;             // b == c bitwise (symmetric cov)
        float term1 = 0.5f * trace;
        float term2 = 0.5f * sqrtf(fmaxf(trace * trace - 4.0f * det, 0.0f));
        float rad = fmaxf(term1 - term2, term1 + term2);
        float inv = 1.0f / det;
        float* fr = out_feat + (size_t)gdest * 7;
        fr[0] = p.x; fr[1] = p.y; fr[2] = d * inv; fr[3] = -b * inv;
        fr[4] = a * inv; fr[5] = op; fr[6] = rad;
        out_order[gdest] = (float)i;
    }
}

extern "C" void kernel_launch(void* const* d_in, const int* in_sizes, int n_in,
                              void* d_out, int out_size, void* d_ws, size_t ws_size,
                              hipStream_t stream) {
    const float2* pos2d   = (const float2*)d_in[0];
    const float4* cov2d   = (const float4*)d_in[1];
    const float*  opacity = (const float*)d_in[2];
    const int N = in_sizes[2];           // opacity element count

    float* out         = (float*)d_out;  // layout: feat | counts | offsets | order
    float* out_feat    = out;
    float* out_counts  = out + (size_t)N * 7;
    float* out_offsets = out_counts + NTILES;
    float* out_order   = out_offsets + NTILES;

    int* gcounts = (int*)d_ws;
    int* gHist   = gcounts + NTILES;

    int nchunks = (N + CHUNK - 1) / CHUNK;   // 977 for N=2M (K2 supports <=1024)

    hipMemsetAsync(gcounts, 0, NTILES * sizeof(int), stream);
    k_hist<<<nchunks, 256, 0, stream>>>(pos2d, gHist, gcounts, N);
    k_scan<<<NTILES, 256, 0, stream>>>(gcounts, gHist, out_counts, out_offsets, nchunks);
    k_scatter<<<nchunks, 256, 0, stream>>>(pos2d, cov2d, opacity, gHist,
                                           out_feat, out_order, N);
}

// Round 5
// 161.612 us; speedup vs baseline: 1.0666x; 1.0666x over previous
//
#include <hip/hip_runtime.h>

#define NT 16
#define NTILES 256
#define INV_TILE (1.0f/64.0f)
#define CHUNK 2048          // points per block
#define WPT 512             // points per wave
#define ROUNDS 8            // WPT/64

__device__ __forceinline__ int tile_of(float x, float y) {
    int tx = (int)floorf(x * INV_TILE);
    tx = tx < 0 ? 0 : (tx > NT - 1 ? NT - 1 : tx);
    int ty = (int)floorf(y * INV_TILE);
    ty = ty < 0 ? 0 : (ty > NT - 1 ? NT - 1 : ty);
    return ty * NT + tx;
}

// 64-lane same-tile group mask via 8 ballots (tile id is 8 bits).
__device__ __forceinline__ unsigned long long match_mask(int t, bool valid) {
    unsigned long long m = ~0ull;
#pragma unroll
    for (int b = 0; b < 8; ++b) {
        unsigned long long bal = __ballot((t >> b) & 1);
        m &= ((t >> b) & 1) ? bal : ~bal;
    }
    m &= __ballot(valid);
    return m;
}

// K1: per-chunk histogram + per-point block-local sorted position.
// Writes: gHist[c][t] = chunk totals (pre-scan), gcounts totals,
//         P[i] = (t<<16) | ldest  (ldest < 2048).
__global__ __launch_bounds__(256) void k_hist(const float2* __restrict__ pos2d,
                                              int* __restrict__ gHist,
                                              int* __restrict__ gcounts,
                                              unsigned int* __restrict__ P,
                                              int N) {
    __shared__ int cnt[4][NTILES];
    __shared__ unsigned short pwr[CHUNK];   // wave-local rank within (wave,tile)
    __shared__ unsigned char  tld[CHUNK];   // tile id
    __shared__ int wsum[4];
    const int tid = threadIdx.x;
    const int wl = tid >> 6, lane = tid & 63;
    const int base_i = blockIdx.x * CHUNK;
#pragma unroll
    for (int k = 0; k < 4; ++k) cnt[wl][lane + 64 * k] = 0;     // wave-private

    // ---- pass 1: ballots -> hist + wave-local stable rank ----
    for (int r = 0; r < ROUNDS; ++r) {
        int o = wl * WPT + r * 64 + lane;
        int i = base_i + o;
        bool valid = i < N;
        int t = 0;
        if (valid) { float2 p = pos2d[i]; t = tile_of(p.x, p.y); }
        tld[o] = (unsigned char)t;
        unsigned long long m = match_mask(t, valid);
        if (valid) {
            unsigned long long below = m & ((1ull << lane) - 1ull);
            int rank = __popcll(below);
            int b = cnt[wl][t];                     // lockstep read-before-write
            if (below == 0ull) cnt[wl][t] = b + __popcll(m);
            pwr[o] = (unsigned short)(b + rank);
        }
    }
    __syncthreads();

    // ---- block scan (thread tid = tile): per-wave block-local bases ----
    int c0 = cnt[0][tid], c1 = cnt[1][tid], c2 = cnt[2][tid], c3 = cnt[3][tid];
    int tot = c0 + c1 + c2 + c3;
    gHist[(size_t)blockIdx.x * NTILES + tid] = tot;             // pre-scan totals
    if (tot) atomicAdd(&gcounts[tid], tot);
    int x = tot;
#pragma unroll
    for (int s = 1; s < 64; s <<= 1) {
        int y = __shfl_up(x, s);
        if (lane >= s) x += y;
    }
    if (lane == 63) wsum[wl] = x;
    __syncthreads();
    int wpre = 0;
    for (int u = 0; u < wl; ++u) wpre += wsum[u];
    int excl = wpre + x - tot;                  // block-exclusive start of tile tid
    cnt[0][tid] = excl;
    cnt[1][tid] = excl + c0;
    cnt[2][tid] = excl + c0 + c1;
    cnt[3][tid] = excl + c0 + c1 + c2;
    __syncthreads();

    // ---- pass 2: emit packed (t, ldest), coalesced ----
    int nvalid = N - base_i; if (nvalid > CHUNK) nvalid = CHUNK;
    for (int o = tid; o < nvalid; o += 256) {
        int t = tld[o];
        int ldest = cnt[o >> 9][t] + pwr[o];
        P[base_i + o] = ((unsigned int)t << 16) | (unsigned int)ldest;
    }
}

// K2: one block per tile t. Cross-tile exclusive offset + scan of per-chunk
// totals column into global per-(chunk,tile) bases, in place. Sentinel end
// row at NWA. Supports NWA <= 1024.
__global__ __launch_bounds__(256) void k_scan(const int* __restrict__ gcounts,
                                              int* __restrict__ gHist,
                                              float* __restrict__ out_counts,
                                              float* __restrict__ out_offsets,
                                              int NWA) {
    const int t = blockIdx.x;
    const int tid = threadIdx.x;
    const int wl = tid >> 6, lane = tid & 63;
    __shared__ int sdata[NTILES];
    __shared__ int wsum[4];

    int v = (tid < t) ? gcounts[tid] : 0;            // offset_t = sum_{u<t}
    sdata[tid] = v;
    __syncthreads();
#pragma unroll
    for (int s = 128; s > 0; s >>= 1) {
        if (tid < s) sdata[tid] += sdata[tid + s];
        __syncthreads();
    }
    int offset_t = sdata[0];
    if (tid == 0) {
        int ct = gcounts[t];
        out_counts[t]  = (float)ct;
        out_offsets[t] = (float)offset_t;
        gHist[(size_t)NWA * NTILES + t] = offset_t + ct;   // sentinel end row
    }

    int vals[4];
    const int base_row = tid * 4;
#pragma unroll
    for (int k = 0; k < 4; ++k) {
        int row = base_row + k;
        vals[k] = (row < NWA) ? gHist[(size_t)row * NTILES + t] : 0;
    }
    int tv = vals[0] + vals[1] + vals[2] + vals[3];
    int x = tv;
#pragma unroll
    for (int s = 1; s < 64; s <<= 1) {
        int y = __shfl_up(x, s);
        if (lane >= s) x += y;
    }
    if (lane == 63) wsum[wl] = x;
    __syncthreads();
    int wprefix = 0;
    for (int u = 0; u < wl; ++u) wprefix += wsum[u];
    int running = offset_t + wprefix + (x - tv);
#pragma unroll
    for (int k = 0; k < 4; ++k) {
        int row = base_row + k;
        if (row < NWA) gHist[(size_t)row * NTILES + t] = running;
        running += vals[k];
    }
}

// K3: streaming stage + coalesced write-out. No ballots, 2 barriers.
// stage: coalesced P + cov2d + opacity -> SoA LDS at precomputed ldest.
// write: conic/radius math; pos2d gather (L3-hot); coalesced per-tile runs.
__global__ __launch_bounds__(256) void k_scatter(const float2* __restrict__ pos2d,
                                                 const float4* __restrict__ cov2d,
                                                 const float*  __restrict__ opacity,
                                                 const int*    __restrict__ gBase,
                                                 const unsigned int* __restrict__ P,
                                                 float* __restrict__ out_feat,
                                                 float* __restrict__ out_order,
                                                 int N) {
    __shared__ float fA[CHUNK], fB[CHUNK], fD[CHUNK], fOp[CHUNK];
    __shared__ unsigned int slotPk[CHUNK];    // (t<<16)|o at sorted pos
    __shared__ int gbase[NTILES];
    __shared__ int tstart[NTILES];
    __shared__ int wsum[4];

    const int tid = threadIdx.x;
    const int wl = tid >> 6, lane = tid & 63;
    const int base_i = blockIdx.x * CHUNK;

    // per-tile global base + count for this chunk (2 coalesced 1KB rows)
    int gb = gBase[(size_t)blockIdx.x * NTILES + tid];
    int ge = gBase[(size_t)(blockIdx.x + 1) * NTILES + tid];
    gbase[tid] = gb;
    int tot = ge - gb;
    int x = tot;                                    // exclusive scan -> tstart
#pragma unroll
    for (int s = 1; s < 64; s <<= 1) {
        int y = __shfl_up(x, s);
        if (lane >= s) x += y;
    }
    if (lane == 63) wsum[wl] = x;
    __syncthreads();
    int wpre = 0;
    for (int u = 0; u < wl; ++u) wpre += wsum[u];
    tstart[tid] = wpre + x - tot;
    __syncthreads();

    // ---- stage: one coalesced streaming pass ----
    int nvalid = N - base_i; if (nvalid > CHUNK) nvalid = CHUNK;
    for (int o = tid; o < nvalid; o += 256) {
        int i = base_i + o;
        unsigned int pk = P[i];
        int t = pk >> 16;
        int ldest = pk & 0xFFFF;
        float4 cv = cov2d[i];
        float op = opacity[i];
        fA[ldest] = cv.x; fB[ldest] = cv.y; fD[ldest] = cv.w; fOp[ldest] = op;
        slotPk[ldest] = ((unsigned int)t << 16) | (unsigned int)o;
    }
    __syncthreads();

    // ---- write-out: conic/radius + coalesced per-tile segments ----
    for (int j = tid; j < nvalid; j += 256) {
        unsigned int pk = slotPk[j];
        int t = pk >> 16;
        int o = pk & 0xFFFF;
        int gdest = gbase[t] + (j - tstart[t]);
        int i = base_i + o;
        float2 p = pos2d[i];                   // gather, L3-hot (16KB/block window)
        float a = fA[j], b = fB[j], d = fD[j], op = fOp[j];
        float trace = a + d;
        float det = a * d - b * b;             // b == c bitwise (symmetric cov)
        float term1 = 0.5f * trace;
        float term2 = 0.5f * sqrtf(fmaxf(trace * trace - 4.0f * det, 0.0f));
        float rad = fmaxf(term1 - term2, term1 + term2);
        float inv = 1.0f / det;
        float* fr = out_feat + (size_t)gdest * 7;
        fr[0] = p.x; fr[1] = p.y; fr[2] = d * inv; fr[3] = -b * inv;
        fr[4] = a * inv; fr[5] = op; fr[6] = rad;
        out_order[gdest] = (float)i;
    }
}

extern "C" void kernel_launch(void* const* d_in, const int* in_sizes, int n_in,
                              void* d_out, int out_size, void* d_ws, size_t ws_size,
                              hipStream_t stream) {
    const float2* pos2d   = (const float2*)d_in[0];
    const float4* cov2d   = (const float4*)d_in[1];
    const float*  opacity = (const float*)d_in[2];
    const int N = in_sizes[2];           // opacity element count

    float* out         = (float*)d_out;  // layout: feat | counts | offsets | order
    float* out_feat    = out;
    float* out_counts  = out + (size_t)N * 7;
    float* out_offsets = out_counts + NTILES;
    float* out_order   = out_offsets + NTILES;

    int nchunks = (N + CHUNK - 1) / CHUNK;   // 977 for N=2M (k_scan supports <=1024)

    int* gcounts     = (int*)d_ws;                         // [256]
    int* gHist       = gcounts + NTILES;                   // [(nc+1) x 256]
    unsigned int* P  = (unsigned int*)(gHist + (size_t)(nchunks + 1) * NTILES); // [N]

    hipMemsetAsync(gcounts, 0, NTILES * sizeof(int), stream);
    k_hist<<<nchunks, 256, 0, stream>>>(pos2d, gHist, gcounts, P, N);
    k_scan<<<NTILES, 256, 0, stream>>>(gcounts, gHist, out_counts, out_offsets, nchunks);
    k_scatter<<<nchunks, 256, 0, stream>>>(pos2d, cov2d, opacity, gHist, P,
                                           out_feat, out_order, N);
}

// Round 6
// 157.197 us; speedup vs baseline: 1.0966x; 1.0281x over previous
//
#include <hip/hip_runtime.h>

#define NT 16
#define NTILES 256
#define INV_TILE (1.0f/64.0f)
#define CHUNK 2048          // points per block

__device__ __forceinline__ int tile_of(float x, float y) {
    int tx = (int)floorf(x * INV_TILE);
    tx = tx < 0 ? 0 : (tx > NT - 1 ? NT - 1 : tx);
    int ty = (int)floorf(y * INV_TILE);
    ty = ty < 0 ? 0 : (ty > NT - 1 ? NT - 1 : ty);
    return ty * NT + tx;
}

// 64-lane same-tile group mask via 8 ballots (tile id is 8 bits).
__device__ __forceinline__ unsigned long long match_mask(int t, bool valid) {
    unsigned long long m = ~0ull;
#pragma unroll
    for (int b = 0; b < 8; ++b) {
        unsigned long long bal = __ballot((t >> b) & 1);
        m &= ((t >> b) & 1) ? bal : ~bal;
    }
    m &= __ballot(valid);
    return m;
}

// K1: per-chunk histogram + per-point block-local sorted position.
// 512 threads = 8 waves, 256 pts/wave, 4 ballot rounds (short serial chain).
// Writes: gHist[c][t] = chunk totals (pre-scan), gcounts totals,
//         P[i] = (t<<16) | ldest  (ldest < 2048).
__global__ __launch_bounds__(512) void k_hist(const float2* __restrict__ pos2d,
                                              int* __restrict__ gHist,
                                              int* __restrict__ gcounts,
                                              unsigned int* __restrict__ P,
                                              int N) {
    __shared__ int cnt[8][NTILES];          // per-wave counters
    __shared__ unsigned short pwr[CHUNK];   // wave-local stable rank
    __shared__ unsigned char  tld[CHUNK];   // tile id
    __shared__ int wsum[4];
    const int tid = threadIdx.x;
    const int wl = tid >> 6, lane = tid & 63;
    const int base_i = blockIdx.x * CHUNK;
#pragma unroll
    for (int k = 0; k < 4; ++k) cnt[wl][lane + 64 * k] = 0;     // wave-private

    // ---- pass 1: ballots -> hist + wave-local stable rank ----
#pragma unroll
    for (int r = 0; r < 4; ++r) {
        int o = wl * 256 + r * 64 + lane;
        int i = base_i + o;
        bool valid = i < N;
        int t = 0;
        if (valid) { float2 p = pos2d[i]; t = tile_of(p.x, p.y); }
        tld[o] = (unsigned char)t;
        unsigned long long m = match_mask(t, valid);
        if (valid) {
            unsigned long long below = m & ((1ull << lane) - 1ull);
            int rank = __popcll(below);
            int b = cnt[wl][t];                     // lockstep read-before-write
            if (below == 0ull) cnt[wl][t] = b + __popcll(m);
            pwr[o] = (unsigned short)(b + rank);
        }
    }
    __syncthreads();

    // ---- block scan (threads 0..255, tid = tile): per-wave bases ----
    int c[8], tot = 0, x = 0;
    if (tid < NTILES) {
#pragma unroll
        for (int w = 0; w < 8; ++w) { c[w] = cnt[w][tid]; tot += c[w]; }
        gHist[(size_t)blockIdx.x * NTILES + tid] = tot;         // pre-scan totals
        if (tot) atomicAdd(&gcounts[tid], tot);
        x = tot;
#pragma unroll
        for (int s = 1; s < 64; s <<= 1) {
            int y = __shfl_up(x, s);
            if (lane >= s) x += y;
        }
        if (lane == 63) wsum[wl] = x;
    }
    __syncthreads();
    if (tid < NTILES) {
        int wpre = 0;
        for (int u = 0; u < wl; ++u) wpre += wsum[u];
        int run = wpre + x - tot;               // block-exclusive start of tile tid
#pragma unroll
        for (int w = 0; w < 8; ++w) { cnt[w][tid] = run; run += c[w]; }
    }
    __syncthreads();

    // ---- pass 2: emit packed (t, ldest), coalesced ----
    int nvalid = N - base_i; if (nvalid > CHUNK) nvalid = CHUNK;
    for (int o = tid; o < nvalid; o += 512) {
        int t = tld[o];
        int ldest = cnt[o >> 8][t] + pwr[o];
        P[base_i + o] = ((unsigned int)t << 16) | (unsigned int)ldest;
    }
}

// K2: one block per tile t. Cross-tile exclusive offset + scan of per-chunk
// totals column into global per-(chunk,tile) bases, in place. Sentinel end
// row at NWA. Supports NWA <= 1024.
__global__ __launch_bounds__(256) void k_scan(const int* __restrict__ gcounts,
                                              int* __restrict__ gHist,
                                              float* __restrict__ out_counts,
                                              float* __restrict__ out_offsets,
                                              int NWA) {
    const int t = blockIdx.x;
    const int tid = threadIdx.x;
    const int wl = tid >> 6, lane = tid & 63;
    __shared__ int sdata[NTILES];
    __shared__ int wsum[4];

    int v = (tid < t) ? gcounts[tid] : 0;            // offset_t = sum_{u<t}
    sdata[tid] = v;
    __syncthreads();
#pragma unroll
    for (int s = 128; s > 0; s >>= 1) {
        if (tid < s) sdata[tid] += sdata[tid + s];
        __syncthreads();
    }
    int offset_t = sdata[0];
    if (tid == 0) {
        int ct = gcounts[t];
        out_counts[t]  = (float)ct;
        out_offsets[t] = (float)offset_t;
        gHist[(size_t)NWA * NTILES + t] = offset_t + ct;   // sentinel end row
    }

    int vals[4];
    const int base_row = tid * 4;
#pragma unroll
    for (int k = 0; k < 4; ++k) {
        int row = base_row + k;
        vals[k] = (row < NWA) ? gHist[(size_t)row * NTILES + t] : 0;
    }
    int tv = vals[0] + vals[1] + vals[2] + vals[3];
    int x = tv;
#pragma unroll
    for (int s = 1; s < 64; s <<= 1) {
        int y = __shfl_up(x, s);
        if (lane >= s) x += y;
    }
    if (lane == 63) wsum[wl] = x;
    __syncthreads();
    int wprefix = 0;
    for (int u = 0; u < wl; ++u) wprefix += wsum[u];
    int running = offset_t + wprefix + (x - tv);
#pragma unroll
    for (int k = 0; k < 4; ++k) {
        int row = base_row + k;
        if (row < NWA) gHist[(size_t)row * NTILES + t] = running;
        running += vals[k];
    }
}

// K3: streaming stage + coalesced write-out. 512 threads, LDS ~34 KB ->
// 4 blocks/CU x 8 waves = 32 waves/CU (occupancy cap).
// stage: coalesced P + cov2d -> SoA LDS at precomputed ldest.
// write: conic/radius; pos2d/opacity gathers (L1-resident windows);
//        coalesced per-tile segment runs.
__global__ __launch_bounds__(512) void k_scatter(const float2* __restrict__ pos2d,
                                                 const float4* __restrict__ cov2d,
                                                 const float*  __restrict__ opacity,
                                                 const int*    __restrict__ gBase,
                                                 const unsigned int* __restrict__ P,
                                                 float* __restrict__ out_feat,
                                                 float* __restrict__ out_order,
                                                 int N) {
    __shared__ float fA[CHUNK], fB[CHUNK], fD[CHUNK];
    __shared__ unsigned int slotPk[CHUNK];    // (t<<16)|o at sorted pos
    __shared__ int gbase[NTILES];
    __shared__ int tstart[NTILES];
    __shared__ int wsum[4];

    const int tid = threadIdx.x;
    const int wl = tid >> 6, lane = tid & 63;
    const int base_i = blockIdx.x * CHUNK;

    // per-tile global base + count for this chunk (threads 0..255)
    int gb = 0, tot = 0, x = 0;
    if (tid < NTILES) {
        gb = gBase[(size_t)blockIdx.x * NTILES + tid];
        int ge = gBase[(size_t)(blockIdx.x + 1) * NTILES + tid];
        gbase[tid] = gb;
        tot = ge - gb;
        x = tot;                                    // exclusive scan -> tstart
#pragma unroll
        for (int s = 1; s < 64; s <<= 1) {
            int y = __shfl_up(x, s);
            if (lane >= s) x += y;
        }
        if (lane == 63) wsum[wl] = x;
    }
    __syncthreads();
    if (tid < NTILES) {
        int wpre = 0;
        for (int u = 0; u < wl; ++u) wpre += wsum[u];
        tstart[tid] = wpre + x - tot;
    }
    __syncthreads();

    // ---- stage: one coalesced streaming pass ----
    int nvalid = N - base_i; if (nvalid > CHUNK) nvalid = CHUNK;
    for (int o = tid; o < nvalid; o += 512) {
        int i = base_i + o;
        unsigned int pk = P[i];
        int t = pk >> 16;
        int ldest = pk & 0xFFFF;
        float4 cv = cov2d[i];
        fA[ldest] = cv.x; fB[ldest] = cv.y; fD[ldest] = cv.w;
        slotPk[ldest] = ((unsigned int)t << 16) | (unsigned int)o;
    }
    __syncthreads();

    // ---- write-out: conic/radius + coalesced per-tile segments ----
    for (int j = tid; j < nvalid; j += 512) {
        unsigned int pk = slotPk[j];
        int t = pk >> 16;
        int o = pk & 0xFFFF;
        int gdest = gbase[t] + (j - tstart[t]);
        int i = base_i + o;
        float2 p = pos2d[i];                   // gather, L1-resident (16KB window)
        float op = opacity[i];                 // gather, L1-resident (8KB window)
        float a = fA[j], b = fB[j], d = fD[j];
        float trace = a + d;
        float det = a * d - b * b;             // b == c bitwise (symmetric cov)
        float term1 = 0.5f * trace;
        float term2 = 0.5f * sqrtf(fmaxf(trace * trace - 4.0f * det, 0.0f));
        float rad = fmaxf(term1 - term2, term1 + term2);
        float inv = 1.0f / det;
        float* fr = out_feat + (size_t)gdest * 7;
        fr[0] = p.x; fr[1] = p.y; fr[2] = d * inv; fr[3] = -b * inv;
        fr[4] = a * inv; fr[5] = op; fr[6] = rad;
        out_order[gdest] = (float)i;
    }
}

extern "C" void kernel_launch(void* const* d_in, const int* in_sizes, int n_in,
                              void* d_out, int out_size, void* d_ws, size_t ws_size,
                              hipStream_t stream) {
    const float2* pos2d   = (const float2*)d_in[0];
    const float4* cov2d   = (const float4*)d_in[1];
    const float*  opacity = (const float*)d_in[2];
    const int N = in_sizes[2];           // opacity element count

    float* out         = (float*)d_out;  // layout: feat | counts | offsets | order
    float* out_feat    = out;
    float* out_counts  = out + (size_t)N * 7;
    float* out_offsets = out_counts + NTILES;
    float* out_order   = out_offsets + NTILES;

    int nchunks = (N + CHUNK - 1) / CHUNK;   // 977 for N=2M (k_scan supports <=1024)

    int* gcounts     = (int*)d_ws;                         // [256]
    int* gHist       = gcounts + NTILES;                   // [(nc+1) x 256]
    unsigned int* P  = (unsigned int*)(gHist + (size_t)(nchunks + 1) * NTILES); // [N]

    hipMemsetAsync(gcounts, 0, NTILES * sizeof(int), stream);
    k_hist<<<nchunks, 512, 0, stream>>>(pos2d, gHist, gcounts, P, N);
    k_scan<<<NTILES, 256, 0, stream>>>(gcounts, gHist, out_counts, out_offsets, nchunks);
    k_scatter<<<nchunks, 512, 0, stream>>>(pos2d, cov2d, opacity, gHist, P,
                                           out_feat, out_order, N);
}